// Round 1
// baseline (38678.168 us; speedup 1.0000x reference)
//
#include <hip/hip_runtime.h>
#include <hip/hip_bf16.h>
#include <math.h>

#define BDIM 512
#define TDIM 1024
#define UDIM 512
#define NG   2048   // 4*U

typedef __attribute__((ext_vector_type(8))) short short8;
typedef __attribute__((ext_vector_type(4))) float float4v;

// ---------------- workspace layout ----------------
#define OFF_U0T   ((size_t)0)                       // bf16 [2048][512]  gate-interleaved, transposed
#define SZ_U0T    ((size_t)NG*UDIM*2)
#define OFF_W1U1T (OFF_U0T + SZ_U0T)                // bf16 [2048][1024] (W1 rows 0-511, U1 rows 512-1023)
#define SZ_W1U1T  ((size_t)NG*1024*2)
#define OFF_W0P   (OFF_W1U1T + SZ_W1U1T)            // f32 [3][2048] permuted
#define SZ_W0P    ((size_t)3*NG*4)
#define OFF_B0P   (OFF_W0P + SZ_W0P)                // f32 [2048] permuted
#define OFF_B1P   (OFF_B0P + (size_t)NG*4)
#define OFF_STATE (OFF_B1P + (size_t)NG*4)
#define SZ_HB     ((size_t)BDIM*UDIM*2)
#define SZ_HF     ((size_t)BDIM*UDIM*4)
#define OFF_H0B   (OFF_STATE)                       // bf16 x2 (ping-pong)
#define OFF_H1B   (OFF_H0B + 2*SZ_HB)
#define OFF_H0F   (OFF_H1B + 2*SZ_HB)               // f32 master x2
#define OFF_H1F   (OFF_H0F + 2*SZ_HF)
#define OFF_C0    (OFF_H1F + 2*SZ_HF)               // f32 in-place
#define OFF_C1    (OFF_C0 + SZ_HF)
#define STATE_BYTES (OFF_C1 + SZ_HF - OFF_STATE)    // 8 MB exactly

__device__ __forceinline__ float sigm(float x) { return 1.0f / (1.0f + expf(-x)); }

// Weight prep: bf16 convert + transpose to [n',k] + gate-interleave columns
// n' = unit*4 + gate  <-  orig col = gate*512 + unit
__global__ void prep_kernel(const float* __restrict__ W0, const float* __restrict__ U0,
                            const float* __restrict__ b0, const float* __restrict__ W1,
                            const float* __restrict__ U1, const float* __restrict__ b1,
                            char* __restrict__ ws)
{
    int idx = blockIdx.x * 256 + threadIdx.x;   // 2048*1024 total
    int n = idx >> 10;
    int k = idx & 1023;
    int oc = (n & 3) * UDIM + (n >> 2);
    __hip_bfloat16* U0t = (__hip_bfloat16*)(ws + OFF_U0T);
    __hip_bfloat16* Wc  = (__hip_bfloat16*)(ws + OFF_W1U1T);
    float* W0p = (float*)(ws + OFF_W0P);
    float* b0p = (float*)(ws + OFF_B0P);
    float* b1p = (float*)(ws + OFF_B1P);
    if (k < 512) U0t[(size_t)n * 512 + k] = __float2bfloat16(U0[(size_t)k * NG + oc]);
    float wv = (k < 512) ? W1[(size_t)k * NG + oc] : U1[(size_t)(k - 512) * NG + oc];
    Wc[(size_t)n * 1024 + k] = __float2bfloat16(wv);
    if (k < 3) W0p[k * NG + n] = W0[(size_t)k * NG + oc];
    if (k == 0) { b0p[n] = b0[oc]; b1p[n] = b1[oc]; }
}

// One LSTM-cell 128x128 output tile: bf16 MFMA GEMM + fused gate/time-gate epilogue.
// A = [512, KTOT] bf16 (KTOT=512: Aa only; KTOT=1024: Aa rows k<512, Ab k>=512, both lda=512)
// Wt = [2048, KTOT] bf16 transposed permuted weights.
__device__ void cell_tile(
    char* smem, int tile, int t, int KTOT,
    const __hip_bfloat16* __restrict__ Aa, const __hip_bfloat16* __restrict__ Ab,
    const __hip_bfloat16* __restrict__ Wt,
    const float* __restrict__ bias, const float* __restrict__ W0p,
    const float* __restrict__ inputs, const float* __restrict__ times,
    const float* __restrict__ tau, const float* __restrict__ sph,
    float* __restrict__ cst,
    const float* __restrict__ hf_prev, float* __restrict__ hf_cur,
    __hip_bfloat16* __restrict__ hb_cur)
{
    const int tid = threadIdx.x;
    const int mtile = tile >> 4;     // 0..3  (rows mtile*128)
    const int ntile = tile & 15;     // 0..15 (perm cols ntile*128 = units ntile*32..+31)
    short* sA = (short*)smem;                 // [128][40] bf16, pad to 40 (80B rows, 16B aligned)
    short* sB = (short*)(smem + 10240);       // [128][40]
    const int wave = tid >> 6, lane = tid & 63;
    const int wr = (wave & 1) * 64, wc = (wave >> 1) * 64;
    const int lr = lane & 15, lq = lane >> 4;

    const float4v zero4 = {0.0f, 0.0f, 0.0f, 0.0f};
    float4v acc[4][4];
#pragma unroll
    for (int i = 0; i < 4; ++i)
#pragma unroll
        for (int j = 0; j < 4; ++j) acc[i][j] = zero4;

    for (int kc = 0; kc < KTOT; kc += 32) {
        __syncthreads();
        const __hip_bfloat16* Abase = (kc < 512) ? Aa : Ab;
        const int kk = (kc < 512) ? kc : kc - 512;
        // stage A-tile (128x32) and B-tile (128x32) : 16B per thread per tile-half
#pragma unroll
        for (int l = 0; l < 2; ++l) {
            int li = tid + 256 * l;
            int r = li >> 2, q = li & 3;
            short8 av = *(const short8*)(Abase + (size_t)(mtile * 128 + r) * UDIM + kk + q * 8);
            *(short8*)&sA[r * 40 + q * 8] = av;
            short8 bv = *(const short8*)(Wt + (size_t)(ntile * 128 + r) * KTOT + kc + q * 8);
            *(short8*)&sB[r * 40 + q * 8] = bv;
        }
        __syncthreads();
        short8 aF[4], bF[4];
#pragma unroll
        for (int i = 0; i < 4; ++i) aF[i] = *(const short8*)&sA[(wr + i * 16 + lr) * 40 + lq * 8];
#pragma unroll
        for (int j = 0; j < 4; ++j) bF[j] = *(const short8*)&sB[(wc + j * 16 + lr) * 40 + lq * 8];
#pragma unroll
        for (int i = 0; i < 4; ++i)
#pragma unroll
            for (int j = 0; j < 4; ++j)
                acc[i][j] = __builtin_amdgcn_mfma_f32_16x16x32_bf16(aF[i], bF[j], acc[i][j], 0, 0, 0);
    }

    // Epilogue: two col-halves (units ch*16..+15 of this tile) through LDS.
    float* Z = (float*)smem;   // [128][68] f32 (aliases sA/sB)
    for (int ch = 0; ch < 2; ++ch) {
        __syncthreads();
        if ((wave >> 1) == ch) {
#pragma unroll
            for (int i = 0; i < 4; ++i)
#pragma unroll
                for (int j = 0; j < 4; ++j)
#pragma unroll
                    for (int r = 0; r < 4; ++r)
                        Z[(wr + i * 16 + lq * 4 + r) * 68 + (j * 16 + lr)] = acc[i][j][r];
        }
        __syncthreads();
        for (int rep = 0; rep < 8; ++rep) {
            int p = rep * 256 + tid;
            int row = p >> 4, ul = p & 15;
            float4v z = *(const float4v*)&Z[row * 68 + ul * 4];
            int b = mtile * 128 + row;
            int u = ntile * 32 + ch * 16 + ul;
            int pc = u * 4;
            float zi = z[0] + bias[pc + 0];
            float zf = z[1] + bias[pc + 1];
            float zg = z[2] + bias[pc + 2];
            float zo = z[3] + bias[pc + 3];
            if (W0p) {   // layer 0: x @ W0 in fp32 (K=3)
                const float* xp = &inputs[((size_t)b * TDIM + t) * 3];
                float x0 = xp[0], x1 = xp[1], x2 = xp[2];
                zi += x0 * W0p[pc + 0] + x1 * W0p[NG + pc + 0] + x2 * W0p[2 * NG + pc + 0];
                zf += x0 * W0p[pc + 1] + x1 * W0p[NG + pc + 1] + x2 * W0p[2 * NG + pc + 1];
                zg += x0 * W0p[pc + 2] + x1 * W0p[NG + pc + 2] + x2 * W0p[2 * NG + pc + 2];
                zo += x0 * W0p[pc + 3] + x1 * W0p[NG + pc + 3] + x2 * W0p[2 * NG + pc + 3];
            }
            float ig = sigm(zi), fg = sigm(zf), gg = tanhf(zg), og = sigm(zo);
            size_t su = (size_t)b * UDIM + u;
            float cp = cst[su];
            float cc = fg * cp + ig * gg;
            float hc = og * tanhf(cc);
            float tt = times[(size_t)b * TDIM + t];
            float tv = tau[u], sv = sph[u];
            float ph = fmodf(tt - sv, tv);
            ph = (ph < 0.0f ? ph + tv : ph) / tv;   // jnp.mod semantics: in [0,1)
            float kg = (ph < 0.5f * 0.05f) ? (ph * (2.0f / 0.05f))
                     : (ph < 0.05f ? 2.0f - ph * (2.0f / 0.05f) : 0.001f * ph);
            float cn = kg * cc + (1.0f - kg) * cp;
            float hp = hf_prev[su];
            float hn = kg * hc + (1.0f - kg) * hp;
            cst[su] = cn;
            hf_cur[su] = hn;
            hb_cur[su] = __float2bfloat16(hn);
        }
    }
}

// Diagonal-wavefront stage: blocks 0-63 layer0[t=s], 64-127 layer1[t=s-1], 128-135 FC+softmax[t=s-2]
__global__ __launch_bounds__(256, 2)
void stage_kernel(int s,
    const float* __restrict__ inputs, const float* __restrict__ times,
    const float* __restrict__ tau0, const float* __restrict__ s0,
    const float* __restrict__ tau1, const float* __restrict__ s1,
    const float* __restrict__ Wfc, const float* __restrict__ bfc,
    char* __restrict__ ws, float* __restrict__ out)
{
    __shared__ __align__(16) char smem[34816];
    const int blk = blockIdx.x;
    __hip_bfloat16* h0b[2] = {(__hip_bfloat16*)(ws + OFF_H0B), (__hip_bfloat16*)(ws + OFF_H0B + SZ_HB)};
    __hip_bfloat16* h1b[2] = {(__hip_bfloat16*)(ws + OFF_H1B), (__hip_bfloat16*)(ws + OFF_H1B + SZ_HB)};
    float* h0f[2] = {(float*)(ws + OFF_H0F), (float*)(ws + OFF_H0F + SZ_HF)};
    float* h1f[2] = {(float*)(ws + OFF_H1F), (float*)(ws + OFF_H1F + SZ_HF)};
    float* c0 = (float*)(ws + OFF_C0);
    float* c1 = (float*)(ws + OFF_C1);
    const int pA = (s + 1) & 1;   // parity of step s-1
    const int pB = s & 1;         // parity of step s (== s-2)

    if (blk < 64) {
        if (s >= TDIM) return;
        cell_tile(smem, blk, s, 512,
                  h0b[pA], nullptr, (const __hip_bfloat16*)(ws + OFF_U0T),
                  (const float*)(ws + OFF_B0P), (const float*)(ws + OFF_W0P),
                  inputs, times, tau0, s0,
                  c0, h0f[pA], h0f[pB], h0b[pB]);
    } else if (blk < 128) {
        if (s < 1 || s > TDIM) return;
        cell_tile(smem, blk - 64, s - 1, 1024,
                  h0b[pA], h1b[pB], (const __hip_bfloat16*)(ws + OFF_W1U1T),
                  (const float*)(ws + OFF_B1P), nullptr,
                  inputs, times, tau1, s1,
                  c1, h1f[pB], h1f[pA], h1b[pA]);
    } else {
        if (s < 2) return;
        int t = s - 2;
        const float* h = h1f[pB];
        int wave = threadIdx.x >> 6, lane = threadIdx.x & 63;
        int rbase = (blk - 128) * 64 + wave * 16;
        for (int ri = 0; ri < 16; ++ri) {
            int row = rbase + ri;
            float a[10];
#pragma unroll
            for (int c = 0; c < 10; ++c) a[c] = 0.0f;
            for (int it = 0; it < 8; ++it) {
                float hv = h[(size_t)row * UDIM + it * 64 + lane];
                const float* wp = &Wfc[(size_t)(it * 64 + lane) * 10];
#pragma unroll
                for (int c = 0; c < 10; ++c) a[c] += hv * wp[c];
            }
#pragma unroll
            for (int c = 0; c < 10; ++c)
                for (int m = 32; m; m >>= 1) a[c] += __shfl_xor(a[c], m, 64);
            if (lane == 0) {
                float mx = -1e30f;
#pragma unroll
                for (int c = 0; c < 10; ++c) { a[c] += bfc[c]; mx = fmaxf(mx, a[c]); }
                float sum = 0.0f;
#pragma unroll
                for (int c = 0; c < 10; ++c) { a[c] = expf(a[c] - mx); sum += a[c]; }
                float inv = 1.0f / sum;
                float* op = &out[((size_t)row * TDIM + t) * 10];
#pragma unroll
                for (int c = 0; c < 10; ++c) op[c] = a[c] * inv;
            }
        }
    }
}

extern "C" void kernel_launch(void* const* d_in, const int* in_sizes, int n_in,
                              void* d_out, int out_size, void* d_ws, size_t ws_size,
                              hipStream_t stream) {
    const float* inputs = (const float*)d_in[0];
    const float* times  = (const float*)d_in[1];
    const float* W0   = (const float*)d_in[2];
    const float* U0   = (const float*)d_in[3];
    const float* b0   = (const float*)d_in[4];
    const float* tau0 = (const float*)d_in[5];
    const float* s0   = (const float*)d_in[6];
    const float* W1   = (const float*)d_in[7];
    const float* U1   = (const float*)d_in[8];
    const float* b1   = (const float*)d_in[9];
    const float* tau1 = (const float*)d_in[10];
    const float* s1   = (const float*)d_in[11];
    const float* Wfc  = (const float*)d_in[12];
    const float* bfc  = (const float*)d_in[13];
    float* out = (float*)d_out;
    char* ws = (char*)d_ws;

    hipMemsetAsync(ws + OFF_STATE, 0, STATE_BYTES, stream);
    prep_kernel<<<(NG * 1024) / 256, 256, 0, stream>>>(W0, U0, b0, W1, U1, b1, ws);
    for (int s = 0; s < TDIM + 2; ++s)
        stage_kernel<<<136, 256, 0, stream>>>(s, inputs, times, tau0, s0, tau1, s1,
                                              Wfc, bfc, ws, out);
}